// Round 9
// baseline (114.522 us; speedup 1.0000x reference)
//
#include <hip/hip_runtime.h>

#define HH 384
#define WW 384
#define HWP (HH * WW)   // 147456
#define DD 64
#define BB 2
#define NG2 8           // 8 phases, 2 channel-groups (8 channels) each

#define TX 64
#define TY 4
#define LR 20           // TY + 16 halo rows
#define LC 80           // TX + 16 halo cols
#define LN (LR * LC)    // 1600 slots (uint4 = 16B each -> 25.6 KB)
#define NBX 6
#define NBY 96
#define NWG (NBX * NBY * BB)   // 1152 = 8 * 144

typedef __fp16 h2v __attribute__((ext_vector_type(2)));
union h4 { uint2 u; h2v h[2]; };

#if __has_builtin(__builtin_amdgcn_fdot2)
#define DOT4(acc, a, b)                                           \
    acc = __builtin_amdgcn_fdot2((a).h[0], (b).h[0], acc, false);   \
    acc = __builtin_amdgcn_fdot2((a).h[1], (b).h[1], acc, false)
#else
#define DOT4(acc, a, b)                                     \
    acc = fmaf((float)(a).h[0].x, (float)(b).h[0].x, acc);   \
    acc = fmaf((float)(a).h[0].y, (float)(b).h[0].y, acc);   \
    acc = fmaf((float)(a).h[1].x, (float)(b).h[1].x, acc);   \
    acc = fmaf((float)(a).h[1].y, (float)(b).h[1].y, acc)
#endif

// K1: stats + repack to f16 8-channel planes hp4[b][g2][y][x] (16 B / px)
__global__ __launch_bounds__(256) void stats_pack_k(const float* __restrict__ des,
                                                    uint4* __restrict__ hp4,
                                                    float* __restrict__ ssq,
                                                    float* __restrict__ smm) {
    int idx = blockIdx.x * 256 + threadIdx.x;        // 0 .. 294911
    int b = idx / HWP;
    int p = idx - b * HWP;
    const float* base = des + (size_t)b * DD * HWP + p;
    uint4* hb = hp4 + (size_t)b * NG2 * HWP + p;
    float ss = 0.f, s0 = 0.f;
#pragma unroll 2
    for (int g = 0; g < NG2; ++g) {
        float v0 = base[(size_t)(8 * g + 0) * HWP];
        float v1 = base[(size_t)(8 * g + 1) * HWP];
        float v2 = base[(size_t)(8 * g + 2) * HWP];
        float v3 = base[(size_t)(8 * g + 3) * HWP];
        float v4 = base[(size_t)(8 * g + 4) * HWP];
        float v5 = base[(size_t)(8 * g + 5) * HWP];
        float v6 = base[(size_t)(8 * g + 6) * HWP];
        float v7 = base[(size_t)(8 * g + 7) * HWP];
        ss = fmaf(v0, v0, ss); ss = fmaf(v1, v1, ss);
        ss = fmaf(v2, v2, ss); ss = fmaf(v3, v3, ss);
        ss = fmaf(v4, v4, ss); ss = fmaf(v5, v5, ss);
        ss = fmaf(v6, v6, ss); ss = fmaf(v7, v7, ss);
        s0 += ((v0 + v1) + (v2 + v3)) + ((v4 + v5) + (v6 + v7));
        h4 a, c;
        a.h[0] = __builtin_amdgcn_cvt_pkrtz(v0, v1);
        a.h[1] = __builtin_amdgcn_cvt_pkrtz(v2, v3);
        c.h[0] = __builtin_amdgcn_cvt_pkrtz(v4, v5);
        c.h[1] = __builtin_amdgcn_cvt_pkrtz(v6, v7);
        uint4 w; w.x = a.u.x; w.y = a.u.y; w.z = c.u.x; w.w = c.u.y;
        hb[(size_t)g * HWP] = w;
    }
    ssq[idx] = ss;
    smm[idx] = s0;
}

// K2: dilated 5x5 dot stencil on packed f16 8-ch planes. 1 px/thread,
// tile 64x4, single 25.6KB LDS buffer, 8 phases, b128 LDS ops throughout.
__global__ __launch_bounds__(256) void ssd_k(const uint4* __restrict__ hp4,
                                             const float* __restrict__ ssq,
                                             const float* __restrict__ smm,
                                             float* __restrict__ out) {
    __shared__ uint4 lds[LN];   // 25,600 B
    const int tx = threadIdx.x;            // 0..63
    const int ty = threadIdx.y;            // 0..3
    const int tid = ty * 64 + tx;

    // XCD-aware bijective swizzle (1152 = 8 * 144)
    int bid = blockIdx.x;
    int swz = (bid & 7) * 144 + (bid >> 3);
    int b  = swz / (NBX * NBY);
    int r0 = swz % (NBX * NBY);
    int by = r0 / NBX;
    int bx = r0 - by * NBX;
    const int x0 = bx * TX, y0 = by * TY;
    const int x = x0 + tx;
    const int y = y0 + ty;

    // Clamped global offsets for this thread's 7 staging slots (1600 = 6*256 + 64)
    int goff[7];
#pragma unroll
    for (int k = 0; k < 7; ++k) {
        int i = tid + 256 * k;
        if (i < LN) {
            int r = i / LC, c = i - (i / LC) * LC;
            int gy = y0 + r - 8; gy = gy < 0 ? 0 : (gy > HH - 1 ? HH - 1 : gy);
            int gx = x0 + c - 8; gx = gx < 0 ? 0 : (gx > WW - 1 ? WW - 1 : gx);
            goff[k] = gy * WW + gx;
        } else {
            goff[k] = 0;
        }
    }

    const uint4* hb = hp4 + (size_t)b * NG2 * HWP;
    uint4 rg[7];

    auto ISSUE = [&](int g) {
        const uint4* p = hb + (size_t)g * HWP;
#pragma unroll
        for (int k = 0; k < 7; ++k) rg[k] = p[goff[k]];
    };
    auto FIN = [&]() {
#pragma unroll
        for (int k = 0; k < 6; ++k) lds[tid + 256 * k] = rg[k];
        if (tid < LN - 1536) lds[tid + 1536] = rg[6];
    };

    float acc[25];
#pragma unroll
    for (int n = 0; n < 25; ++n) acc[n] = 0.f;

    const int base = ty * LC + tx;
    auto COMPUTE = [&]() {
        uint4 cc = lds[base + 8 * LC + 8];         // center (m=2,j=2)
        h4 ca, cb; ca.u.x = cc.x; ca.u.y = cc.y; cb.u.x = cc.z; cb.u.y = cc.w;
#pragma unroll
        for (int m = 0; m < 5; ++m)
#pragma unroll
            for (int j = 0; j < 5; ++j) {
                uint4 v = lds[base + (4 * m) * LC + 4 * j];
                h4 va, vb; va.u.x = v.x; va.u.y = v.y; vb.u.x = v.z; vb.u.y = v.w;
                DOT4(acc[m * 5 + j], ca, va);
                DOT4(acc[m * 5 + j], cb, vb);
            }
    };

    // single-buffer pipeline: ISSUE(g+1) | COMPUTE(g) | bar | FIN | bar
    ISSUE(0);
    FIN();
    __syncthreads();
#pragma unroll 1
    for (int g = 0; g < NG2; ++g) {
        if (g + 1 < NG2) ISSUE(g + 1);
        COMPUTE();
        __syncthreads();                 // all waves done reading buffer
        if (g + 1 < NG2) {
            FIN();                       // overwrite with next phase's data
            __syncthreads();             // buffer ready
        }
    }

    // epilogue: stage ssq tile (f32) into the buffer
    __syncthreads();
    float* lsq = (float*)&lds[0];   // 1600 floats (6.4 KB)
    {
        const float* sp = ssq + (size_t)b * HWP;
        float r[7];
#pragma unroll
        for (int k = 0; k < 7; ++k) r[k] = sp[goff[k]];
#pragma unroll
        for (int k = 0; k < 6; ++k) lsq[tid + 256 * k] = r[k];
        if (tid < LN - 1536) lsq[tid + 1536] = r[6];
    }
    __syncthreads();

    // clamped tap coords for exact-zero self taps
    int yc[5], xc[5];
#pragma unroll
    for (int m = 0; m < 5; ++m) {
        int yy = y - 8 + 4 * m; yc[m] = yy < 0 ? 0 : (yy > HH - 1 ? HH - 1 : yy);
        int xx = x - 8 + 4 * m; xc[m] = xx < 0 ? 0 : (xx > WW - 1 ? WW - 1 : xx);
    }

    float ssA = lsq[base + 8 * LC + 8];
    float mu = smm[(size_t)b * HWP + y * WW + x] * (1.0f / 64);
    float var = ssA * (1.0f / 64) - mu * mu;
    float sabs = sqrtf(fmaxf(var, 0.f));
    float L = 0.f;
#pragma unroll
    for (int m = 0; m < 5; ++m)
#pragma unroll
        for (int j = 0; j < 5; ++j) {
            float ssB = lsq[base + (4 * m) * LC + 4 * j];
            float d2 = fmaxf(ssA + ssB - 2.f * acc[m * 5 + j], 0.f);
            float sq = sqrtf(d2);
            L += (yc[m] == y && xc[j] == x) ? 0.f : sq;
        }
    float srel = L * (1.0f / 25);
    float sraw = sabs * srel;
    out[(size_t)b * HWP + y * WW + x] = sraw / (sraw + 1.f);
}

extern "C" void kernel_launch(void* const* d_in, const int* in_sizes, int n_in,
                              void* d_out, int out_size, void* d_ws, size_t ws_size,
                              hipStream_t stream) {
    const float* des = (const float*)d_in[0];
    float* out = (float*)d_out;

    uint4* hp4 = (uint4*)d_ws;                                   // BB*NG2*HWP uint4
    float* ssq = (float*)(hp4 + (size_t)BB * NG2 * HWP);         // BB*HWP
    float* smm = ssq + (size_t)BB * HWP;                         // BB*HWP

    stats_pack_k<<<dim3((BB * HWP) / 256), dim3(256), 0, stream>>>(des, hp4, ssq, smm);
    ssd_k<<<dim3(NWG), dim3(64, 4), 0, stream>>>(hp4, ssq, smm, out);
}

// Round 10
// 60.328 us; speedup vs baseline: 1.8983x; 1.8983x over previous
//
#include <hip/hip_runtime.h>

#define HH 384
#define WW 384
#define HWP (HH * WW)   // 147456
#define DD 64
#define BB 2
#define NG2 8           // 8 phases, 8 channels each

#define TX 64
#define TY 4
#define LR 20           // TY + 16 halo rows
#define LC 80           // TX + 16 halo cols
#define LN (LR * LC)    // 1600 slots (uint4 = 16B each -> 25.6 KB per buffer)
#define NBX 6
#define NBY 96
#define NWG (NBX * NBY * BB)   // 1152 = 8 * 144

typedef __fp16 h2v __attribute__((ext_vector_type(2)));
union h4 { uint2 u; h2v h[2]; };

#if __has_builtin(__builtin_amdgcn_fdot2)
#define DOT4(acc, a, b)                                           \
    acc = __builtin_amdgcn_fdot2((a).h[0], (b).h[0], acc, false);   \
    acc = __builtin_amdgcn_fdot2((a).h[1], (b).h[1], acc, false)
#else
#define DOT4(acc, a, b)                                     \
    acc = fmaf((float)(a).h[0].x, (float)(b).h[0].x, acc);   \
    acc = fmaf((float)(a).h[0].y, (float)(b).h[0].y, acc);   \
    acc = fmaf((float)(a).h[1].x, (float)(b).h[1].x, acc);   \
    acc = fmaf((float)(a).h[1].y, (float)(b).h[1].y, acc)
#endif

// K1: stats + repack to f16 8-channel planes hp4[b][g2][y][x] (16 B / px)
__global__ __launch_bounds__(256) void stats_pack_k(const float* __restrict__ des,
                                                    uint4* __restrict__ hp4,
                                                    float* __restrict__ ssq,
                                                    float* __restrict__ smm) {
    int idx = blockIdx.x * 256 + threadIdx.x;        // 0 .. 294911
    int b = idx / HWP;
    int p = idx - b * HWP;
    const float* base = des + (size_t)b * DD * HWP + p;
    uint4* hb = hp4 + (size_t)b * NG2 * HWP + p;
    float ss = 0.f, s0 = 0.f;
#pragma unroll 2
    for (int g = 0; g < NG2; ++g) {
        float v0 = base[(size_t)(8 * g + 0) * HWP];
        float v1 = base[(size_t)(8 * g + 1) * HWP];
        float v2 = base[(size_t)(8 * g + 2) * HWP];
        float v3 = base[(size_t)(8 * g + 3) * HWP];
        float v4 = base[(size_t)(8 * g + 4) * HWP];
        float v5 = base[(size_t)(8 * g + 5) * HWP];
        float v6 = base[(size_t)(8 * g + 6) * HWP];
        float v7 = base[(size_t)(8 * g + 7) * HWP];
        ss = fmaf(v0, v0, ss); ss = fmaf(v1, v1, ss);
        ss = fmaf(v2, v2, ss); ss = fmaf(v3, v3, ss);
        ss = fmaf(v4, v4, ss); ss = fmaf(v5, v5, ss);
        ss = fmaf(v6, v6, ss); ss = fmaf(v7, v7, ss);
        s0 += ((v0 + v1) + (v2 + v3)) + ((v4 + v5) + (v6 + v7));
        h4 a, c;
        a.h[0] = __builtin_amdgcn_cvt_pkrtz(v0, v1);
        a.h[1] = __builtin_amdgcn_cvt_pkrtz(v2, v3);
        c.h[0] = __builtin_amdgcn_cvt_pkrtz(v4, v5);
        c.h[1] = __builtin_amdgcn_cvt_pkrtz(v6, v7);
        uint4 w; w.x = a.u.x; w.y = a.u.y; w.z = c.u.x; w.w = c.u.y;
        hb[(size_t)g * HWP] = w;
    }
    ssq[idx] = ss;
    smm[idx] = s0;
}

// K2: dilated 5x5 dot stencil on packed f16 8-ch planes. 1 px/thread,
// tile 64x4, DOUBLE-buffered LDS (short rg live range: ISSUE->FIN->COMPUTE),
// 8 phases, 1 barrier/phase, b128 LDS ops throughout.
__global__ __launch_bounds__(256) void ssd_k(const uint4* __restrict__ hp4,
                                             const float* __restrict__ ssq,
                                             const float* __restrict__ smm,
                                             float* __restrict__ out) {
    __shared__ uint4 lds[2][LN];   // 51,200 B
    const int tx = threadIdx.x;            // 0..63
    const int ty = threadIdx.y;            // 0..3
    const int tid = ty * 64 + tx;

    // XCD-aware bijective swizzle (1152 = 8 * 144)
    int bid = blockIdx.x;
    int swz = (bid & 7) * 144 + (bid >> 3);
    int b  = swz / (NBX * NBY);
    int r0 = swz % (NBX * NBY);
    int by = r0 / NBX;
    int bx = r0 - by * NBX;
    const int x0 = bx * TX, y0 = by * TY;
    const int x = x0 + tx;
    const int y = y0 + ty;

    // Clamped global offsets for this thread's 7 staging slots (1600 = 6*256 + 64)
    int goff[7];
#pragma unroll
    for (int k = 0; k < 7; ++k) {
        int i = tid + 256 * k;
        if (i < LN) {
            int r = i / LC, c = i - (i / LC) * LC;
            int gy = y0 + r - 8; gy = gy < 0 ? 0 : (gy > HH - 1 ? HH - 1 : gy);
            int gx = x0 + c - 8; gx = gx < 0 ? 0 : (gx > WW - 1 ? WW - 1 : gx);
            goff[k] = gy * WW + gx;
        } else {
            goff[k] = 0;
        }
    }

    const uint4* hb = hp4 + (size_t)b * NG2 * HWP;

    // load channel-plane g and immediately store to lds[bb] (short reg live range)
    auto STAGE = [&](int g, int bb) {
        const uint4* p = hb + (size_t)g * HWP;
        uint4 rg[7];
#pragma unroll
        for (int k = 0; k < 7; ++k) rg[k] = p[goff[k]];
#pragma unroll
        for (int k = 0; k < 6; ++k) lds[bb][tid + 256 * k] = rg[k];
        if (tid < LN - 1536) lds[bb][tid + 1536] = rg[6];
    };

    float acc[25];
#pragma unroll
    for (int n = 0; n < 25; ++n) acc[n] = 0.f;

    const int base = ty * LC + tx;
    auto COMPUTE = [&](int bb) {
        uint4 cc = lds[bb][base + 8 * LC + 8];     // center (m=2,j=2)
        h4 ca, cb; ca.u.x = cc.x; ca.u.y = cc.y; cb.u.x = cc.z; cb.u.y = cc.w;
#pragma unroll
        for (int m = 0; m < 5; ++m)
#pragma unroll
            for (int j = 0; j < 5; ++j) {
                uint4 v = lds[bb][base + (4 * m) * LC + 4 * j];
                h4 va, vb; va.u.x = v.x; va.u.y = v.y; vb.u.x = v.z; vb.u.y = v.w;
                DOT4(acc[m * 5 + j], ca, va);
                DOT4(acc[m * 5 + j], cb, vb);
            }
    };

    // double-buffer pipeline, 1 barrier/phase:
    //   phase g: STAGE(g+1 -> buf^1) ; COMPUTE(buf) ; barrier
    STAGE(0, 0);
    __syncthreads();
#pragma unroll 1
    for (int g = 0; g < NG2; g += 2) {
        if (g + 1 < NG2) STAGE(g + 1, 1);
        COMPUTE(0);
        __syncthreads();
        if (g + 2 < NG2) STAGE(g + 2, 0);
        COMPUTE(1);
        __syncthreads();
    }

    // epilogue: stage ssq tile (f32) into buffer 0
    float* lsq = (float*)&lds[0][0];   // 1600 floats (6.4 KB)
    {
        const float* sp = ssq + (size_t)b * HWP;
        float r[7];
#pragma unroll
        for (int k = 0; k < 7; ++k) r[k] = sp[goff[k]];
#pragma unroll
        for (int k = 0; k < 6; ++k) lsq[tid + 256 * k] = r[k];
        if (tid < LN - 1536) lsq[tid + 1536] = r[6];
    }
    __syncthreads();

    // clamped tap coords for exact-zero self taps
    int yc[5], xc[5];
#pragma unroll
    for (int m = 0; m < 5; ++m) {
        int yy = y - 8 + 4 * m; yc[m] = yy < 0 ? 0 : (yy > HH - 1 ? HH - 1 : yy);
        int xx = x - 8 + 4 * m; xc[m] = xx < 0 ? 0 : (xx > WW - 1 ? WW - 1 : xx);
    }

    float ssA = lsq[base + 8 * LC + 8];
    float mu = smm[(size_t)b * HWP + y * WW + x] * (1.0f / 64);
    float var = ssA * (1.0f / 64) - mu * mu;
    float sabs = sqrtf(fmaxf(var, 0.f));
    float L = 0.f;
#pragma unroll
    for (int m = 0; m < 5; ++m)
#pragma unroll
        for (int j = 0; j < 5; ++j) {
            float ssB = lsq[base + (4 * m) * LC + 4 * j];
            float d2 = fmaxf(ssA + ssB - 2.f * acc[m * 5 + j], 0.f);
            float sq = sqrtf(d2);
            L += (yc[m] == y && xc[j] == x) ? 0.f : sq;
        }
    float srel = L * (1.0f / 25);
    float sraw = sabs * srel;
    out[(size_t)b * HWP + y * WW + x] = sraw / (sraw + 1.f);
}

extern "C" void kernel_launch(void* const* d_in, const int* in_sizes, int n_in,
                              void* d_out, int out_size, void* d_ws, size_t ws_size,
                              hipStream_t stream) {
    const float* des = (const float*)d_in[0];
    float* out = (float*)d_out;

    uint4* hp4 = (uint4*)d_ws;                                   // BB*NG2*HWP uint4
    float* ssq = (float*)(hp4 + (size_t)BB * NG2 * HWP);         // BB*HWP
    float* smm = ssq + (size_t)BB * HWP;                         // BB*HWP

    stats_pack_k<<<dim3((BB * HWP) / 256), dim3(256), 0, stream>>>(des, hp4, ssq, smm);
    ssd_k<<<dim3(NWG), dim3(64, 4), 0, stream>>>(hp4, ssq, smm, out);
}

// Round 11
// 57.894 us; speedup vs baseline: 1.9781x; 1.0420x over previous
//
#include <hip/hip_runtime.h>

#define HH 384
#define WW 384
#define HWP (HH * WW)   // 147456
#define DD 64
#define BB 2
#define NG2 8           // 8 phases, 8 channels each

#define TX 32
#define TY 8            // tile 32x8; thread (tx,ty) ty<4 owns px (y0+ty, y0+ty+4)
#define LR 24           // TY + 16 halo rows
#define LC 48           // TX + 16 halo cols
#define LN (LR * LC)    // 1152 slots (uint4) = 18.4 KB/buffer; x2 = 36.9 KB
#define NT 128          // threads/block (2 waves)
#define SPT (LN / NT)   // 9 staging slots/thread, exact
#define NBX (WW / TX)   // 12
#define NBY (HH / TY)   // 48
#define NWG (NBX * NBY * BB)   // 1152 = 8 * 144

typedef __fp16 h2v __attribute__((ext_vector_type(2)));
union h4 { uint2 u; h2v h[2]; };

#if __has_builtin(__builtin_amdgcn_fdot2)
#define DOT4(acc, a, b)                                           \
    acc = __builtin_amdgcn_fdot2((a).h[0], (b).h[0], acc, false);   \
    acc = __builtin_amdgcn_fdot2((a).h[1], (b).h[1], acc, false)
#else
#define DOT4(acc, a, b)                                     \
    acc = fmaf((float)(a).h[0].x, (float)(b).h[0].x, acc);   \
    acc = fmaf((float)(a).h[0].y, (float)(b).h[0].y, acc);   \
    acc = fmaf((float)(a).h[1].x, (float)(b).h[1].x, acc);   \
    acc = fmaf((float)(a).h[1].y, (float)(b).h[1].y, acc)
#endif

// K1: stats + repack to f16 8-channel planes hp4[b][g2][y][x] (16 B / px)
__global__ __launch_bounds__(256) void stats_pack_k(const float* __restrict__ des,
                                                    uint4* __restrict__ hp4,
                                                    float* __restrict__ ssq,
                                                    float* __restrict__ smm) {
    int idx = blockIdx.x * 256 + threadIdx.x;        // 0 .. 294911
    int b = idx / HWP;
    int p = idx - b * HWP;
    const float* base = des + (size_t)b * DD * HWP + p;
    uint4* hb = hp4 + (size_t)b * NG2 * HWP + p;
    float ss = 0.f, s0 = 0.f;
#pragma unroll 2
    for (int g = 0; g < NG2; ++g) {
        float v0 = base[(size_t)(8 * g + 0) * HWP];
        float v1 = base[(size_t)(8 * g + 1) * HWP];
        float v2 = base[(size_t)(8 * g + 2) * HWP];
        float v3 = base[(size_t)(8 * g + 3) * HWP];
        float v4 = base[(size_t)(8 * g + 4) * HWP];
        float v5 = base[(size_t)(8 * g + 5) * HWP];
        float v6 = base[(size_t)(8 * g + 6) * HWP];
        float v7 = base[(size_t)(8 * g + 7) * HWP];
        ss = fmaf(v0, v0, ss); ss = fmaf(v1, v1, ss);
        ss = fmaf(v2, v2, ss); ss = fmaf(v3, v3, ss);
        ss = fmaf(v4, v4, ss); ss = fmaf(v5, v5, ss);
        ss = fmaf(v6, v6, ss); ss = fmaf(v7, v7, ss);
        s0 += ((v0 + v1) + (v2 + v3)) + ((v4 + v5) + (v6 + v7));
        h4 a, c;
        a.h[0] = __builtin_amdgcn_cvt_pkrtz(v0, v1);
        a.h[1] = __builtin_amdgcn_cvt_pkrtz(v2, v3);
        c.h[0] = __builtin_amdgcn_cvt_pkrtz(v4, v5);
        c.h[1] = __builtin_amdgcn_cvt_pkrtz(v6, v7);
        uint4 w; w.x = a.u.x; w.y = a.u.y; w.z = c.u.x; w.w = c.u.y;
        hb[(size_t)g * HWP] = w;
    }
    ssq[idx] = ss;
    smm[idx] = s0;
}

// K2: dilated 5x5 dot stencil, 2 px/thread (y, y+4) sharing 5/6 tap rows.
// Tile 32x8, 128 threads, f16 b128 LDS double-buffer, 8 phases.
__global__ __launch_bounds__(NT) void ssd_k(const uint4* __restrict__ hp4,
                                            const float* __restrict__ ssq,
                                            const float* __restrict__ smm,
                                            float* __restrict__ out) {
    __shared__ uint4 lds[2][LN];   // 36,864 B
    const int tx = threadIdx.x;            // 0..31
    const int ty = threadIdx.y;            // 0..3
    const int tid = ty * 32 + tx;

    // XCD-aware bijective swizzle (1152 = 8 * 144)
    int bid = blockIdx.x;
    int swz = (bid & 7) * 144 + (bid >> 3);
    int b  = swz / (NBX * NBY);
    int r0 = swz % (NBX * NBY);
    int by = r0 / NBX;
    int bx = r0 - by * NBX;
    const int x0 = bx * TX, y0 = by * TY;
    const int x = x0 + tx;
    const int y = y0 + ty;                 // px A; px B = y + 4

    // Clamped global offsets for this thread's 9 staging slots (1152 = 9*128)
    int goff[SPT];
#pragma unroll
    for (int k = 0; k < SPT; ++k) {
        int i = tid + NT * k;
        int r = i / LC, c = i - (i / LC) * LC;
        int gy = y0 + r - 8; gy = gy < 0 ? 0 : (gy > HH - 1 ? HH - 1 : gy);
        int gx = x0 + c - 8; gx = gx < 0 ? 0 : (gx > WW - 1 ? WW - 1 : gx);
        goff[k] = gy * WW + gx;
    }

    const uint4* hb = hp4 + (size_t)b * NG2 * HWP;

    // load channel-plane g, store to lds[bb] (short reg live range)
    auto STAGE = [&](int g, int bb) {
        const uint4* p = hb + (size_t)g * HWP;
        uint4 rg[SPT];
#pragma unroll
        for (int k = 0; k < SPT; ++k) rg[k] = p[goff[k]];
#pragma unroll
        for (int k = 0; k < SPT; ++k) lds[bb][tid + NT * k] = rg[k];
    };

    float accA[25], accB[25];
#pragma unroll
    for (int n = 0; n < 25; ++n) { accA[n] = 0.f; accB[n] = 0.f; }

    const int base = ty * LC + tx;   // row ty, col tx (+8 halo handled below)
    auto COMPUTE = [&](int bb) {
        const uint4* L = lds[bb];
        uint4 cc0 = L[base + 8 * LC + 8];    // center px A (row ty+8, col tx+8)
        uint4 cc1 = L[base + 12 * LC + 8];   // center px B (row ty+12)
        h4 cA0, cA1, cB0, cB1;
        cA0.u.x = cc0.x; cA0.u.y = cc0.y; cA1.u.x = cc0.z; cA1.u.y = cc0.w;
        cB0.u.x = cc1.x; cB0.u.y = cc1.y; cB1.u.x = cc1.z; cB1.u.y = cc1.w;
#pragma unroll
        for (int m = 0; m < 6; ++m)
#pragma unroll
            for (int j = 0; j < 5; ++j) {
                uint4 v = L[base + (4 * m) * LC + 4 * j];
                h4 va, vb;
                va.u.x = v.x; va.u.y = v.y; vb.u.x = v.z; vb.u.y = v.w;
                if (m < 5) {
                    int n = m * 5 + j;
                    DOT4(accA[n], cA0, va);
                    DOT4(accA[n], cA1, vb);
                }
                if (m >= 1) {
                    int n = (m - 1) * 5 + j;
                    DOT4(accB[n], cB0, va);
                    DOT4(accB[n], cB1, vb);
                }
            }
    };

    // double-buffer pipeline, 1 barrier/phase
    STAGE(0, 0);
    __syncthreads();
#pragma unroll 1
    for (int g = 0; g < NG2; g += 2) {
        if (g + 1 < NG2) STAGE(g + 1, 1);
        COMPUTE(0);
        __syncthreads();
        if (g + 2 < NG2) STAGE(g + 2, 0);
        COMPUTE(1);
        __syncthreads();
    }

    // epilogue: stage ssq tile (f32) into buffer 0
    float* lsq = (float*)&lds[0][0];   // 1152 floats (4.6 KB)
    {
        const float* sp = ssq + (size_t)b * HWP;
        float r[SPT];
#pragma unroll
        for (int k = 0; k < SPT; ++k) r[k] = sp[goff[k]];
#pragma unroll
        for (int k = 0; k < SPT; ++k) lsq[tid + NT * k] = r[k];
    }
    __syncthreads();

    float sv[6][5];
#pragma unroll
    for (int m = 0; m < 6; ++m)
#pragma unroll
        for (int j = 0; j < 5; ++j)
            sv[m][j] = lsq[base + (4 * m) * LC + 4 * j];

    // clamped tap coords for exact-zero self taps
    int yc[6], xc[5];
#pragma unroll
    for (int m = 0; m < 6; ++m) {
        int yy = y - 8 + 4 * m; yc[m] = yy < 0 ? 0 : (yy > HH - 1 ? HH - 1 : yy);
    }
#pragma unroll
    for (int j = 0; j < 5; ++j) {
        int xx = x - 8 + 4 * j; xc[j] = xx < 0 ? 0 : (xx > WW - 1 ? WW - 1 : xx);
    }

#pragma unroll
    for (int a = 0; a < 2; ++a) {
        const int py = y + 4 * a;
        const float* acc = a ? accB : accA;
        float ssA = sv[2 + a][2];
        float mu = smm[(size_t)b * HWP + py * WW + x] * (1.0f / 64);
        float var = ssA * (1.0f / 64) - mu * mu;
        float sabs = sqrtf(fmaxf(var, 0.f));
        float L = 0.f;
#pragma unroll
        for (int m = 0; m < 5; ++m)
#pragma unroll
            for (int j = 0; j < 5; ++j) {
                float ssB = sv[m + a][j];
                float d2 = fmaxf(ssA + ssB - 2.f * acc[m * 5 + j], 0.f);
                float sq = sqrtf(d2);
                L += (yc[m + a] == py && xc[j] == x) ? 0.f : sq;
            }
        float srel = L * (1.0f / 25);
        float sraw = sabs * srel;
        out[(size_t)b * HWP + py * WW + x] = sraw / (sraw + 1.f);
    }
}

extern "C" void kernel_launch(void* const* d_in, const int* in_sizes, int n_in,
                              void* d_out, int out_size, void* d_ws, size_t ws_size,
                              hipStream_t stream) {
    const float* des = (const float*)d_in[0];
    float* out = (float*)d_out;

    uint4* hp4 = (uint4*)d_ws;                                   // BB*NG2*HWP uint4
    float* ssq = (float*)(hp4 + (size_t)BB * NG2 * HWP);         // BB*HWP
    float* smm = ssq + (size_t)BB * HWP;                         // BB*HWP

    stats_pack_k<<<dim3((BB * HWP) / 256), dim3(256), 0, stream>>>(des, hp4, ssq, smm);
    ssd_k<<<dim3(NWG), dim3(TX, 4), 0, stream>>>(hp4, ssq, smm, out);
}

// Round 12
// 47.684 us; speedup vs baseline: 2.4017x; 1.2141x over previous
//
#include <hip/hip_runtime.h>

#define HH 384
#define WW 384
#define HWP (HH * WW)   // 147456
#define DD 64
#define BB 2
#define NG2 8           // 8 phases, 8 channels each

#define TX 32
#define TY 8            // tile 32x8; thread (tx,ty) ty<4 owns px (y0+ty, y0+ty+4)
#define LR 24           // TY + 16 halo rows
#define LC 48           // TX + 16 halo cols
#define LN (LR * LC)    // 1152 slots (uint4) = 18.4 KB/buffer; x2 = 36.9 KB
#define NT 128          // threads/block (2 waves)
#define SPT (LN / NT)   // 9 staging slots/thread, exact
#define NBX (WW / TX)   // 12
#define NBY (HH / TY)   // 48
#define NWG (NBX * NBY * BB)   // 1152 = 8 * 144

typedef __fp16 h2v __attribute__((ext_vector_type(2)));
union h4 { uint2 u; h2v h[2]; };

#if __has_builtin(__builtin_amdgcn_fdot2)
#define DOT4(acc, a, b)                                           \
    acc = __builtin_amdgcn_fdot2((a).h[0], (b).h[0], acc, false);   \
    acc = __builtin_amdgcn_fdot2((a).h[1], (b).h[1], acc, false)
#else
#define DOT4(acc, a, b)                                     \
    acc = fmaf((float)(a).h[0].x, (float)(b).h[0].x, acc);   \
    acc = fmaf((float)(a).h[0].y, (float)(b).h[0].y, acc);   \
    acc = fmaf((float)(a).h[1].x, (float)(b).h[1].x, acc);   \
    acc = fmaf((float)(a).h[1].y, (float)(b).h[1].y, acc)
#endif

// async global->LDS, 16B per lane (vmcnt-counted)
__device__ __forceinline__ void gl_lds16(const uint4* g, uint4* l) {
    __builtin_amdgcn_global_load_lds(
        (const __attribute__((address_space(1))) unsigned int*)(const void*)g,
        (__attribute__((address_space(3))) unsigned int*)(void*)l, 16, 0, 0);
}

#define FENCE() asm volatile("" ::: "memory")

// K1: stats + repack to f16 8-channel planes hp4[b][g2][y][x] (16 B / px)
__global__ __launch_bounds__(256) void stats_pack_k(const float* __restrict__ des,
                                                    uint4* __restrict__ hp4,
                                                    float* __restrict__ ssq,
                                                    float* __restrict__ smm) {
    int idx = blockIdx.x * 256 + threadIdx.x;        // 0 .. 294911
    int b = idx / HWP;
    int p = idx - b * HWP;
    const float* base = des + (size_t)b * DD * HWP + p;
    uint4* hb = hp4 + (size_t)b * NG2 * HWP + p;
    float ss = 0.f, s0 = 0.f;
#pragma unroll 2
    for (int g = 0; g < NG2; ++g) {
        float v0 = base[(size_t)(8 * g + 0) * HWP];
        float v1 = base[(size_t)(8 * g + 1) * HWP];
        float v2 = base[(size_t)(8 * g + 2) * HWP];
        float v3 = base[(size_t)(8 * g + 3) * HWP];
        float v4 = base[(size_t)(8 * g + 4) * HWP];
        float v5 = base[(size_t)(8 * g + 5) * HWP];
        float v6 = base[(size_t)(8 * g + 6) * HWP];
        float v7 = base[(size_t)(8 * g + 7) * HWP];
        ss = fmaf(v0, v0, ss); ss = fmaf(v1, v1, ss);
        ss = fmaf(v2, v2, ss); ss = fmaf(v3, v3, ss);
        ss = fmaf(v4, v4, ss); ss = fmaf(v5, v5, ss);
        ss = fmaf(v6, v6, ss); ss = fmaf(v7, v7, ss);
        s0 += ((v0 + v1) + (v2 + v3)) + ((v4 + v5) + (v6 + v7));
        h4 a, c;
        a.h[0] = __builtin_amdgcn_cvt_pkrtz(v0, v1);
        a.h[1] = __builtin_amdgcn_cvt_pkrtz(v2, v3);
        c.h[0] = __builtin_amdgcn_cvt_pkrtz(v4, v5);
        c.h[1] = __builtin_amdgcn_cvt_pkrtz(v6, v7);
        uint4 w; w.x = a.u.x; w.y = a.u.y; w.z = c.u.x; w.w = c.u.y;
        hb[(size_t)g * HWP] = w;
    }
    ssq[idx] = ss;
    smm[idx] = s0;
}

// K2: dilated 5x5 dot stencil, 2 px/thread (y, y+4) sharing 5/6 tap rows.
// Tile 32x8, 128 threads, f16 b128 LDS double-buffer, 8 phases.
// Staging via global_load_lds + counted vmcnt: next phase's 9 loads stay in
// flight across both barriers (no per-phase vmcnt(0) drain).
__global__ __launch_bounds__(NT) void ssd_k(const uint4* __restrict__ hp4,
                                            const float* __restrict__ ssq,
                                            const float* __restrict__ smm,
                                            float* __restrict__ out) {
    __shared__ uint4 lds[2][LN];   // 36,864 B
    const int tx = threadIdx.x;            // 0..31
    const int ty = threadIdx.y;            // 0..3
    const int tid = ty * 32 + tx;

    // XCD-aware bijective swizzle (1152 = 8 * 144)
    int bid = blockIdx.x;
    int swz = (bid & 7) * 144 + (bid >> 3);
    int b  = swz / (NBX * NBY);
    int r0 = swz % (NBX * NBY);
    int by = r0 / NBX;
    int bx = r0 - by * NBX;
    const int x0 = bx * TX, y0 = by * TY;
    const int x = x0 + tx;
    const int y = y0 + ty;                 // px A; px B = y + 4

    // Clamped global offsets for this thread's 9 staging slots (1152 = 9*128)
    int goff[SPT];
#pragma unroll
    for (int k = 0; k < SPT; ++k) {
        int i = tid + NT * k;
        int r = i / LC, c = i - (i / LC) * LC;
        int gy = y0 + r - 8; gy = gy < 0 ? 0 : (gy > HH - 1 ? HH - 1 : gy);
        int gx = x0 + c - 8; gx = gx < 0 ? 0 : (gx > WW - 1 ? WW - 1 : gx);
        goff[k] = gy * WW + gx;
    }

    const uint4* hb = hp4 + (size_t)b * NG2 * HWP;

    // issue 9 async global->LDS loads for channel-plane g into lds[bb]
    auto STAGE = [&](int g, int bb) {
        const uint4* p = hb + (size_t)g * HWP;
#pragma unroll
        for (int k = 0; k < SPT; ++k)
            gl_lds16(p + goff[k], &lds[bb][tid + NT * k]);
    };

    float accA[25], accB[25];
#pragma unroll
    for (int n = 0; n < 25; ++n) { accA[n] = 0.f; accB[n] = 0.f; }

    const int base = ty * LC + tx;
    auto COMPUTE = [&](int bb) {
        const uint4* L = lds[bb];
        uint4 cc0 = L[base + 8 * LC + 8];    // center px A
        uint4 cc1 = L[base + 12 * LC + 8];   // center px B
        h4 cA0, cA1, cB0, cB1;
        cA0.u.x = cc0.x; cA0.u.y = cc0.y; cA1.u.x = cc0.z; cA1.u.y = cc0.w;
        cB0.u.x = cc1.x; cB0.u.y = cc1.y; cB1.u.x = cc1.z; cB1.u.y = cc1.w;
#pragma unroll
        for (int m = 0; m < 6; ++m)
#pragma unroll
            for (int j = 0; j < 5; ++j) {
                uint4 v = L[base + (4 * m) * LC + 4 * j];
                h4 va, vb;
                va.u.x = v.x; va.u.y = v.y; vb.u.x = v.z; vb.u.y = v.w;
                if (m < 5) {
                    int n = m * 5 + j;
                    DOT4(accA[n], cA0, va);
                    DOT4(accA[n], cA1, vb);
                }
                if (m >= 1) {
                    int n = (m - 1) * 5 + j;
                    DOT4(accB[n], cB0, va);
                    DOT4(accB[n], cB1, vb);
                }
            }
    };

    // 2-deep async pipeline, counted vmcnt, raw barriers:
    //   phase g: wait own 9 g-loads (vmcnt<=9: g+1's stay in flight); barrier;
    //            COMPUTE(g&1); barrier; issue STAGE(g+2 -> g&1)
    STAGE(0, 0);
    STAGE(1, 1);
#pragma unroll 1
    for (int g = 0; g < NG2; ++g) {
        if (g < NG2 - 1) { asm volatile("s_waitcnt vmcnt(9)" ::: "memory"); }
        else             { asm volatile("s_waitcnt vmcnt(0)" ::: "memory"); }
        __builtin_amdgcn_s_barrier();
        FENCE();
        COMPUTE(g & 1);
        FENCE();
        __builtin_amdgcn_s_barrier();
        FENCE();
        if (g + 2 < NG2) STAGE(g + 2, g & 1);
    }

    // epilogue: stage ssq tile (f32) into buffer 0 (nothing in flight now)
    float* lsq = (float*)&lds[0][0];   // 1152 floats (4.6 KB)
    {
        const float* sp = ssq + (size_t)b * HWP;
        float r[SPT];
#pragma unroll
        for (int k = 0; k < SPT; ++k) r[k] = sp[goff[k]];
#pragma unroll
        for (int k = 0; k < SPT; ++k) lsq[tid + NT * k] = r[k];
    }
    __syncthreads();

    float sv[6][5];
#pragma unroll
    for (int m = 0; m < 6; ++m)
#pragma unroll
        for (int j = 0; j < 5; ++j)
            sv[m][j] = lsq[base + (4 * m) * LC + 4 * j];

    // clamped tap coords for exact-zero self taps
    int yc[6], xc[5];
#pragma unroll
    for (int m = 0; m < 6; ++m) {
        int yy = y - 8 + 4 * m; yc[m] = yy < 0 ? 0 : (yy > HH - 1 ? HH - 1 : yy);
    }
#pragma unroll
    for (int j = 0; j < 5; ++j) {
        int xx = x - 8 + 4 * j; xc[j] = xx < 0 ? 0 : (xx > WW - 1 ? WW - 1 : xx);
    }

#pragma unroll
    for (int a = 0; a < 2; ++a) {
        const int py = y + 4 * a;
        const float* acc = a ? accB : accA;
        float ssA = sv[2 + a][2];
        float mu = smm[(size_t)b * HWP + py * WW + x] * (1.0f / 64);
        float var = ssA * (1.0f / 64) - mu * mu;
        float sabs = sqrtf(fmaxf(var, 0.f));
        float L = 0.f;
#pragma unroll
        for (int m = 0; m < 5; ++m)
#pragma unroll
            for (int j = 0; j < 5; ++j) {
                float ssB = sv[m + a][j];
                float d2 = fmaxf(ssA + ssB - 2.f * acc[m * 5 + j], 0.f);
                float sq = sqrtf(d2);
                L += (yc[m + a] == py && xc[j] == x) ? 0.f : sq;
            }
        float srel = L * (1.0f / 25);
        float sraw = sabs * srel;
        out[(size_t)b * HWP + py * WW + x] = sraw / (sraw + 1.f);
    }
}

extern "C" void kernel_launch(void* const* d_in, const int* in_sizes, int n_in,
                              void* d_out, int out_size, void* d_ws, size_t ws_size,
                              hipStream_t stream) {
    const float* des = (const float*)d_in[0];
    float* out = (float*)d_out;

    uint4* hp4 = (uint4*)d_ws;                                   // BB*NG2*HWP uint4
    float* ssq = (float*)(hp4 + (size_t)BB * NG2 * HWP);         // BB*HWP
    float* smm = ssq + (size_t)BB * HWP;                         // BB*HWP

    stats_pack_k<<<dim3((BB * HWP) / 256), dim3(256), 0, stream>>>(des, hp4, ssq, smm);
    ssd_k<<<dim3(NWG), dim3(TX, 4), 0, stream>>>(hp4, ssq, smm, out);
}